// Round 3
// baseline (1048.306 us; speedup 1.0000x reference)
//
#include <hip/hip_runtime.h>
#include <stdint.h>

typedef unsigned short u16;
typedef __bf16 bf16x8 __attribute__((ext_vector_type(8)));
typedef float f32x4 __attribute__((ext_vector_type(4)));

#define B_ 8
#define N_ 7057
#define MTOT 56456
#define SCALING_F (1.0f/64.0f)

// ws layout (bytes, 16-aligned). Total 255,470,848 B = 243.6 MiB.
#define Z_OFF    0ull               // f32 z: 8*7057*64*4 = 14,452,736
#define LORA_OFF 14452736ull        // bf16 lora: 8*7057*64*2 = 7,226,368
#define GIDX_OFF 21679104ull        // int gate_idx[8] (+pad)
#define CWT_OFF  21679360ull        // bf16 conv_wt: 3*9*64*64*2 = 221,184
#define W0B_OFF  21900544ull        // bf16 W0: 1024*1024*2 = 2,097,152
#define WDB_OFF  23997696ull        // bf16 W_down: 64*1024*2 = 131,072
#define WUB_OFF  24128768ull        // bf16 W_up: 1024*64*2 = 131,072
#define UP_OFF   24259840ull        // bf16 up: 8*336*336*64*2 = 115,605,504
#define CO_OFF   139865344ull       // bf16 convout: same size
#define UPB_STRIDE ((size_t)112896 * 64)  // per-batch elems (max rate 4)

__device__ __forceinline__ u16 f2b(float f) {
  __bf16 h = (__bf16)f;           // RNE
  union { __bf16 h; u16 u; } v; v.h = h; return v.u;
}
__device__ __forceinline__ float b2f(u16 u) {
  union { uint32_t i; float f; } v; v.i = ((uint32_t)u) << 16; return v.f;
}
__device__ __forceinline__ void gload_lds16(const void* g, void* l) {
  __builtin_amdgcn_global_load_lds(
      (const __attribute__((address_space(1))) uint32_t*)g,
      (__attribute__((address_space(3))) uint32_t*)l, 16, 0, 0);
}
__device__ __forceinline__ f32x4 mfma16(bf16x8 a, bf16x8 b, f32x4 c) {
  return __builtin_amdgcn_mfma_f32_16x16x32_bf16(a, b, c, 0, 0, 0);
}
__device__ __forceinline__ void cvt_store8(u16* dst, float4 a, float4 b) {
  bf16x8 v;
  v[0] = (__bf16)a.x; v[1] = (__bf16)a.y; v[2] = (__bf16)a.z; v[3] = (__bf16)a.w;
  v[4] = (__bf16)b.x; v[5] = (__bf16)b.y; v[6] = (__bf16)b.z; v[7] = (__bf16)b.w;
  *(bf16x8*)dst = v;
}
__device__ __forceinline__ float cubicw(float t) {
  const float a = -0.75f;
  float at = fabsf(t);
  float w1 = ((a + 2.0f) * at - (a + 3.0f)) * at * at + 1.0f;
  float w2 = (((at - 5.0f) * at + 8.0f) * at - 4.0f) * a;
  return at <= 1.0f ? w1 : (at < 2.0f ? w2 : 0.0f);
}
__device__ __forceinline__ int iclamp(int v, int lo, int hi) { return v < lo ? lo : (v > hi ? hi : v); }
__device__ __forceinline__ int rate_of(int e) { return e == 0 ? 2 : (e == 1 ? 1 : 4); }

// ---------------- Kernel 0: f32 -> bf16 convert (n divisible by 4) ----------------
__global__ __launch_bounds__(256) void cvt_kernel(const float* __restrict__ src, u16* __restrict__ dst, int n) {
  int i = (blockIdx.x * 256 + threadIdx.x) * 4;
  if (i >= n) return;
  float4 v = *(const float4*)(src + i);
  union { u16 u[4]; uint2 q; } p;
  p.u[0] = f2b(v.x); p.u[1] = f2b(v.y); p.u[2] = f2b(v.z); p.u[3] = f2b(v.w);
  *(uint2*)(dst + i) = p.q;
}

// ---------------- Kernel 1: z = x @ W_down^T -> f32 (A reg-stage-converted) ----------------
__global__ __launch_bounds__(256) void zgemm_kernel(const float* __restrict__ x,
                                                    const u16* __restrict__ Wdb,
                                                    float* __restrict__ z) {
  __shared__ u16 As[64 * 32];
  __shared__ u16 Bs[64 * 32];
  const int tid = threadIdx.x;
  const int lane = tid & 63;
  const int w = tid >> 6;
  const int row0 = blockIdx.x * 64;
  f32x4 acc[4] = {{0,0,0,0},{0,0,0,0},{0,0,0,0},{0,0,0,0}};
  const int srow = tid >> 2, sk8 = tid & 3;
  int arow = row0 + srow; if (arow >= MTOT) arow = MTOT - 1;
  const float* agf = x + (size_t)arow * 1024 + sk8 * 8;
  const u16* bg = Wdb + (size_t)srow * 1024 + sk8 * 8;
  u16* al = As + tid * 8;
  u16* bl = Bs + tid * 8;
  const int klo = (lane >> 4) * 8;
  for (int k0 = 0; k0 < 1024; k0 += 32) {
    gload_lds16(bg + k0, bl);
    float4 q0 = *(const float4*)(agf + k0);
    float4 q1 = *(const float4*)(agf + k0 + 4);
    cvt_store8(al, q0, q1);
    __syncthreads();
    bf16x8 a = *(const bf16x8*)(As + (w * 16 + (lane & 15)) * 32 + klo);
#pragma unroll
    for (int fc = 0; fc < 4; ++fc) {
      bf16x8 bb = *(const bf16x8*)(Bs + (fc * 16 + (lane & 15)) * 32 + klo);
      acc[fc] = mfma16(a, bb, acc[fc]);
    }
    __syncthreads();
  }
  const int crow = (lane >> 4) * 4, ccol = lane & 15;
#pragma unroll
  for (int fc = 0; fc < 4; ++fc) {
#pragma unroll
    for (int i = 0; i < 4; ++i) {
      int gr = row0 + w * 16 + crow + i;
      if (gr < MTOT) z[(size_t)gr * 64 + fc * 16 + ccol] = acc[fc][i];
    }
  }
}

// ---------------- Kernel 2a: conv weight transpose f32[e][co][ci][3][3] -> bf16[e][tap][co][ci] ----------------
__global__ __launch_bounds__(256) void convwt_kernel(const float* __restrict__ cw, u16* __restrict__ cwt) {
  int idx = blockIdx.x * 256 + threadIdx.x;          // 3*9*64*64 = 110592 total
  if (idx >= 3 * 9 * 64 * 64) return;
  int ci = idx & 63;
  int co = (idx >> 6) & 63;
  int rest = idx >> 12;           // e*9 + tap
  int tap = rest % 9;
  int e = rest / 9;
  cwt[idx] = f2b(cw[((size_t)(e * 64 + co) * 64 + ci) * 9 + tap]);
}

// ---------------- Kernel 2b: gate (pooled mean -> scores -> argmax) + cls row of lora ----------------
__global__ __launch_bounds__(256) void gate_kernel(const float* __restrict__ z, const float* __restrict__ Wg,
                                                   const float* __restrict__ bg, int* __restrict__ gidx,
                                                   u16* __restrict__ lora) {
  int b = blockIdx.x;
  int tid = threadIdx.x;
  int c = tid & 63, part = tid >> 6;
  __shared__ float red[4][64];
  __shared__ float pl[64];
  const float* zb = z + (size_t)b * N_ * 64;
  float s = 0.0f;
  for (int n = 1 + part; n < N_; n += 4) s += zb[(size_t)n * 64 + c];
  red[part][c] = s;
  __syncthreads();
  if (tid < 64) {
    pl[tid] = (red[0][tid] + red[1][tid] + red[2][tid] + red[3][tid]) * (1.0f / 7056.0f);
    lora[((size_t)b * N_) * 64 + tid] = f2b(zb[tid]);   // cls_embed, NOT scaled
  }
  __syncthreads();
  if (tid == 0) {
    float best = 0.0f; int bi = 0;
    for (int e = 0; e < 3; ++e) {
      float sc = bg[e];
      for (int r = 0; r < 64; ++r) sc += pl[r] * Wg[e * 64 + r];
      if (e == 0 || sc > best) { best = sc; bi = e; }   // first-max semantics
    }
    gidx[b] = bi;
  }
}

// ---------------- Kernel 3: fused separable bicubic upsample (z -> up, layout (y,x,c) bf16) ----------------
__global__ __launch_bounds__(256) void up_kernel(const float* __restrict__ z, const int* __restrict__ gidx,
                                                 u16* __restrict__ up) {
  int b = blockIdx.z;
  int r = rate_of(gidx[b]);
  int H = 84 * r;
  int y = blockIdx.y; if (y >= H) return;
  int c = threadIdx.x & 63, s = threadIdx.x >> 6;
  int x0 = blockIdx.x * 16 + s * 4;
  if (x0 >= H) return;
  float inv = 1.0f / (float)r;
  float sy = (y + 0.5f) * inv - 0.5f;
  float fy = floorf(sy);
  int iy0 = (int)fy;
  float wy[4]; int yi[4];
#pragma unroll
  for (int u = 0; u < 4; ++u) { wy[u] = cubicw(sy - (fy - 1.0f + u)); yi[u] = iclamp(iy0 - 1 + u, 0, 83); }
  const float* zb = z + ((size_t)b * N_ + 1) * 64;
  u16* ub = up + (size_t)b * UPB_STRIDE;
#pragma unroll
  for (int xx = 0; xx < 4; ++xx) {
    int X = x0 + xx; if (X >= H) break;
    float sx = (X + 0.5f) * inv - 0.5f;
    float fx = floorf(sx);
    int ix0 = (int)fx;
    float acc = 0.0f;
#pragma unroll
    for (int v = 0; v < 4; ++v) {
      float wv = cubicw(sx - (fx - 1.0f + v));
      int xiv = iclamp(ix0 - 1 + v, 0, 83);
#pragma unroll
      for (int u = 0; u < 4; ++u)
        acc += wy[u] * wv * zb[((size_t)yi[u] * 84 + xiv) * 64 + c];
    }
    ub[((size_t)y * H + X) * 64 + c] = f2b(acc);
  }
}

// ---------------- Kernel 4: implicit-GEMM 3x3 conv (zero-pad) + bias, selected expert only ----------------
__global__ __launch_bounds__(256) void conv_kernel(const u16* __restrict__ up, const u16* __restrict__ cwt,
                                                   const float* __restrict__ cb, const int* __restrict__ gidx,
                                                   u16* __restrict__ cvo) {
  int b = blockIdx.z;
  int e = gidx[b];
  int r = rate_of(e);
  int H = 84 * r;
  int tx = blockIdx.x, ty = blockIdx.y;
  if (tx * 8 >= H || ty * 8 >= H) return;
  __shared__ u16 halo[100 * 64];   // 10x10 pixels x 64 c_in
  __shared__ u16 Bw[64 * 64];      // [co][ci] for one tap
  int tid = threadIdx.x, lane = tid & 63, w = tid >> 6;
  const u16* ub = up + (size_t)b * UPB_STRIDE;
  for (int li = tid; li < 800; li += 256) {
    int pix = li >> 3, cq = li & 7;
    int hy = pix / 10, hx = pix - hy * 10;
    int iy = ty * 8 - 1 + hy, ix = tx * 8 - 1 + hx;
    uint4 v = {0u, 0u, 0u, 0u};
    if (iy >= 0 && iy < H && ix >= 0 && ix < H)
      v = *(const uint4*)(ub + ((size_t)iy * H + ix) * 64 + cq * 8);
    *(uint4*)(halo + pix * 64 + cq * 8) = v;
  }
  const u16* wte = cwt + (size_t)e * 9 * 4096;
  f32x4 acc[4] = {{0,0,0,0},{0,0,0,0},{0,0,0,0},{0,0,0,0}};
  int p = w * 16 + (lane & 15);
  int py = p >> 3, px = p & 7;
  int klo = (lane >> 4) * 8;
  for (int tap = 0; tap < 9; ++tap) {
    __syncthreads();   // first iter: halo visible; later: prior Bw reads done
    gload_lds16(wte + (size_t)tap * 4096 + tid * 8, Bw + tid * 8);
    gload_lds16(wte + (size_t)tap * 4096 + 2048 + tid * 8, Bw + 2048 + tid * 8);
    __syncthreads();
    int dy = tap / 3, dx = tap - dy * 3;
    const u16* hb = halo + ((py + dy) * 10 + (px + dx)) * 64 + klo;
#pragma unroll
    for (int kk = 0; kk < 2; ++kk) {
      bf16x8 a = *(const bf16x8*)(hb + kk * 32);
#pragma unroll
      for (int fc = 0; fc < 4; ++fc) {
        bf16x8 bb = *(const bf16x8*)(Bw + (fc * 16 + (lane & 15)) * 64 + kk * 32 + klo);
        acc[fc] = mfma16(a, bb, acc[fc]);
      }
    }
  }
  int crow = (lane >> 4) * 4, ccol = lane & 15;
  u16* cvb = cvo + (size_t)b * UPB_STRIDE;
#pragma unroll
  for (int fc = 0; fc < 4; ++fc) {
    int co = fc * 16 + ccol;
    float bias = cb[e * 64 + co];
#pragma unroll
    for (int i = 0; i < 4; ++i) {
      int pd = w * 16 + crow + i;
      int gy = ty * 8 + (pd >> 3), gx = tx * 8 + (pd & 7);
      if (gy < H && gx < H)
        cvb[((size_t)gy * H + gx) * 64 + co] = f2b(acc[fc][i] + bias);
    }
  }
}

// ---------------- Kernel 5: bicubic downsample * SCALING -> lora rows 1..7056 ----------------
__global__ __launch_bounds__(256) void down_kernel(const u16* __restrict__ cvo, const int* __restrict__ gidx,
                                                   u16* __restrict__ lora) {
  int b = blockIdx.z;
  int r = rate_of(gidx[b]);
  int H = 84 * r;
  int tid = threadIdx.x;
  int c = tid & 63, s = tid >> 6;
  int y = blockIdx.y;
  int x = blockIdx.x * 4 + s;
  float fr = (float)r;
  float sy = (y + 0.5f) * fr - 0.5f;
  float fy = floorf(sy);
  int iy0 = (int)fy;
  float wy[4]; int yi[4];
#pragma unroll
  for (int u = 0; u < 4; ++u) { wy[u] = cubicw(sy - (fy - 1.0f + u)); yi[u] = iclamp(iy0 - 1 + u, 0, H - 1); }
  float sx = (x + 0.5f) * fr - 0.5f;
  float fx = floorf(sx);
  int ix0 = (int)fx;
  float wx[4]; int xi[4];
#pragma unroll
  for (int v = 0; v < 4; ++v) { wx[v] = cubicw(sx - (fx - 1.0f + v)); xi[v] = iclamp(ix0 - 1 + v, 0, H - 1); }
  const u16* cbase = cvo + (size_t)b * UPB_STRIDE;
  float acc = 0.0f;
#pragma unroll
  for (int u = 0; u < 4; ++u)
#pragma unroll
    for (int v = 0; v < 4; ++v)
      acc += wy[u] * wx[v] * b2f(cbase[((size_t)yi[u] * H + xi[v]) * 64 + c]);
  lora[((size_t)b * N_ + 1 + y * 84 + x) * 64 + c] = f2b(acc * SCALING_F);
}

// ---------------- Kernel 6: main GEMM out = x@W0^T + b0 + lora@W_up^T (fused K=1024+64) ----------------
#define MAIN_COMPUTE()                                                                       \
  {                                                                                          \
    bf16x8 af[4], bfr[4];                                                                    \
    _Pragma("unroll")                                                                        \
    for (int fm = 0; fm < 4; ++fm)                                                           \
      af[fm] = *(const bf16x8*)(As + (wr * 64 + fm * 16 + (lane & 15)) * 32 + klo);          \
    _Pragma("unroll")                                                                        \
    for (int fc = 0; fc < 4; ++fc)                                                           \
      bfr[fc] = *(const bf16x8*)(Bs + (wc * 64 + fc * 16 + (lane & 15)) * 32 + klo);         \
    _Pragma("unroll")                                                                        \
    for (int fm = 0; fm < 4; ++fm) {                                                         \
      _Pragma("unroll")                                                                      \
      for (int fc = 0; fc < 4; ++fc)                                                         \
        acc[fm][fc] = mfma16(af[fm], bfr[fc], acc[fm][fc]);                                  \
    }                                                                                        \
  }

__global__ __launch_bounds__(256) void main_gemm(const float* __restrict__ x, const u16* __restrict__ W0b,
                                                 const float* __restrict__ b0, const u16* __restrict__ lora,
                                                 const u16* __restrict__ Wub, float* __restrict__ out) {
  __shared__ u16 As[128 * 32];
  __shared__ u16 Bs[128 * 32];
  int tid = threadIdx.x, lane = tid & 63, w = tid >> 6;
  // XCD-chunked swizzle (3536 = 8*442 blocks), col-fastest within a row-panel
  int bid = blockIdx.x;
  int wg = (bid & 7) * 442 + (bid >> 3);
  int row0 = (wg >> 3) * 128, col0 = (wg & 7) * 128;
  int wr = w >> 1, wc = w & 1;
  f32x4 acc[4][4] = {};
  int srow = tid >> 2, sk8 = tid & 3;
  int ar0 = row0 + srow; if (ar0 >= MTOT) ar0 = MTOT - 1;
  int ar1 = row0 + srow + 64; if (ar1 >= MTOT) ar1 = MTOT - 1;
  const float* agf0 = x + (size_t)ar0 * 1024 + sk8 * 8;
  const float* agf1 = x + (size_t)ar1 * 1024 + sk8 * 8;
  const u16* bg0 = W0b + (size_t)(col0 + srow) * 1024 + sk8 * 8;
  const u16* bg1 = W0b + (size_t)(col0 + srow + 64) * 1024 + sk8 * 8;
  u16* al0 = As + tid * 8; u16* al1 = As + tid * 8 + 2048;
  u16* bl0 = Bs + tid * 8; u16* bl1 = Bs + tid * 8 + 2048;
  const int klo = (lane >> 4) * 8;
  for (int k0 = 0; k0 < 1024; k0 += 32) {
    gload_lds16(bg0 + k0, bl0);
    gload_lds16(bg1 + k0, bl1);
    float4 q0 = *(const float4*)(agf0 + k0);
    float4 q1 = *(const float4*)(agf0 + k0 + 4);
    float4 q2 = *(const float4*)(agf1 + k0);
    float4 q3 = *(const float4*)(agf1 + k0 + 4);
    cvt_store8(al0, q0, q1);
    cvt_store8(al1, q2, q3);
    __syncthreads();
    MAIN_COMPUTE();
    __syncthreads();
  }
  // fused lora K-extension (K2 = 64), bf16 sources -> gload_lds
  const u16* lg0 = lora + (size_t)ar0 * 64 + sk8 * 8;
  const u16* lg1 = lora + (size_t)ar1 * 64 + sk8 * 8;
  const u16* ug0 = Wub + (size_t)(col0 + srow) * 64 + sk8 * 8;
  const u16* ug1 = Wub + (size_t)(col0 + srow + 64) * 64 + sk8 * 8;
  for (int k0 = 0; k0 < 64; k0 += 32) {
    gload_lds16(lg0 + k0, al0);
    gload_lds16(lg1 + k0, al1);
    gload_lds16(ug0 + k0, bl0);
    gload_lds16(ug1 + k0, bl1);
    __syncthreads();
    MAIN_COMPUTE();
    __syncthreads();
  }
  int crow = (lane >> 4) * 4, ccol = lane & 15;
#pragma unroll
  for (int fm = 0; fm < 4; ++fm) {
    int grb = row0 + wr * 64 + fm * 16 + crow;
#pragma unroll
    for (int fc = 0; fc < 4; ++fc) {
      int gc = col0 + wc * 64 + fc * 16 + ccol;
      float bias = b0[gc];
#pragma unroll
      for (int i = 0; i < 4; ++i) {
        int gr = grb + i;
        if (gr < MTOT) out[(size_t)gr * 1024 + gc] = acc[fm][fc][i] + bias;
      }
    }
  }
}

extern "C" void kernel_launch(void* const* d_in, const int* in_sizes, int n_in,
                              void* d_out, int out_size, void* d_ws, size_t ws_size,
                              hipStream_t stream) {
  const float* x   = (const float*)d_in[0];
  const float* W0  = (const float*)d_in[1];
  const float* b0  = (const float*)d_in[2];
  const float* Wd  = (const float*)d_in[3];
  const float* Wg  = (const float*)d_in[4];
  const float* bg  = (const float*)d_in[5];
  const float* cw  = (const float*)d_in[6];
  const float* cb  = (const float*)d_in[7];
  const float* Wup = (const float*)d_in[8];
  char* ws = (char*)d_ws;
  float* z    = (float*)(ws + Z_OFF);
  u16* lora   = (u16*)(ws + LORA_OFF);
  int* gidx   = (int*)(ws + GIDX_OFF);
  u16* cwt    = (u16*)(ws + CWT_OFF);
  u16* W0b    = (u16*)(ws + W0B_OFF);
  u16* Wdb    = (u16*)(ws + WDB_OFF);
  u16* Wub    = (u16*)(ws + WUB_OFF);
  u16* up     = (u16*)(ws + UP_OFF);
  u16* cvo    = (u16*)(ws + CO_OFF);
  float* out  = (float*)d_out;

  cvt_kernel<<<dim3(1024), dim3(256), 0, stream>>>(W0, W0b, 1024 * 1024);
  cvt_kernel<<<dim3(64), dim3(256), 0, stream>>>(Wd, Wdb, 64 * 1024);
  cvt_kernel<<<dim3(64), dim3(256), 0, stream>>>(Wup, Wub, 1024 * 64);
  convwt_kernel<<<dim3(432), dim3(256), 0, stream>>>(cw, cwt);
  zgemm_kernel<<<dim3(883), dim3(256), 0, stream>>>(x, Wdb, z);
  gate_kernel<<<dim3(8), dim3(256), 0, stream>>>(z, Wg, bg, gidx, lora);
  up_kernel<<<dim3(21, 336, 8), dim3(256), 0, stream>>>(z, gidx, up);
  conv_kernel<<<dim3(42, 42, 8), dim3(256), 0, stream>>>(up, cwt, cb, gidx, cvo);
  down_kernel<<<dim3(21, 84, 8), dim3(256), 0, stream>>>(cvo, gidx, lora);
  main_gemm<<<dim3(3536), dim3(256), 0, stream>>>(x, W0b, b0, lora, Wub, out);
}

// Round 4
// 642.901 us; speedup vs baseline: 1.6306x; 1.6306x over previous
//
#include <hip/hip_runtime.h>
#include <stdint.h>

typedef unsigned short u16;
typedef __bf16 bf16x8 __attribute__((ext_vector_type(8)));
typedef float f32x4 __attribute__((ext_vector_type(4)));

#define B_ 8
#define N_ 7057
#define MTOT 56456
#define SCALING_F (1.0f/64.0f)

// ws layout (bytes, 16-aligned). Total 255,470,848 B = 243.6 MiB.
#define Z_OFF    0ull               // f32 z: 8*7057*64*4 = 14,452,736
#define LORA_OFF 14452736ull        // bf16 lora: 8*7057*64*2 = 7,226,368
#define GIDX_OFF 21679104ull        // int gate_idx[8] (+pad)
#define CWT_OFF  21679360ull        // bf16 conv_wt: 3*9*64*64*2 = 221,184
#define W0B_OFF  21900544ull        // bf16 W0: 1024*1024*2 = 2,097,152
#define WDB_OFF  23997696ull        // bf16 W_down: 64*1024*2 = 131,072
#define WUB_OFF  24128768ull        // bf16 W_up: 1024*64*2 = 131,072
#define UP_OFF   24259840ull        // bf16 up: 8*336*336*64*2 = 115,605,504 (pp[8][56][64] f32 borrows this pre-up)
#define CO_OFF   139865344ull       // bf16 convout: same size
#define UPB_STRIDE ((size_t)112896 * 64)  // per-batch elems (max rate 4)

__device__ __forceinline__ u16 f2b(float f) {
  __bf16 h = (__bf16)f;           // RNE
  union { __bf16 h; u16 u; } v; v.h = h; return v.u;
}
__device__ __forceinline__ float b2f(u16 u) {
  union { uint32_t i; float f; } v; v.i = ((uint32_t)u) << 16; return v.f;
}
__device__ __forceinline__ void gload_lds16(const void* g, void* l) {
  __builtin_amdgcn_global_load_lds(
      (const __attribute__((address_space(1))) uint32_t*)g,
      (__attribute__((address_space(3))) uint32_t*)l, 16, 0, 0);
}
__device__ __forceinline__ f32x4 mfma16(bf16x8 a, bf16x8 b, f32x4 c) {
  return __builtin_amdgcn_mfma_f32_16x16x32_bf16(a, b, c, 0, 0, 0);
}
__device__ __forceinline__ void cvt_store8(u16* dst, float4 a, float4 b) {
  bf16x8 v;
  v[0] = (__bf16)a.x; v[1] = (__bf16)a.y; v[2] = (__bf16)a.z; v[3] = (__bf16)a.w;
  v[4] = (__bf16)b.x; v[5] = (__bf16)b.y; v[6] = (__bf16)b.z; v[7] = (__bf16)b.w;
  *(bf16x8*)dst = v;
}
__device__ __forceinline__ float cubicw(float t) {
  const float a = -0.75f;
  float at = fabsf(t);
  float w1 = ((a + 2.0f) * at - (a + 3.0f)) * at * at + 1.0f;
  float w2 = (((at - 5.0f) * at + 8.0f) * at - 4.0f) * a;
  return at <= 1.0f ? w1 : (at < 2.0f ? w2 : 0.0f);
}
__device__ __forceinline__ int iclamp(int v, int lo, int hi) { return v < lo ? lo : (v > hi ? hi : v); }
__device__ __forceinline__ int rate_of(int e) { return e == 0 ? 2 : (e == 1 ? 1 : 4); }

// ---------------- Kernel 0: merged f32 -> bf16 weight convert (W0|Wd|Wup -> contiguous dst) ----------------
__global__ __launch_bounds__(256) void cvtall_kernel(const float* __restrict__ W0, const float* __restrict__ Wd,
                                                     const float* __restrict__ Wup, u16* __restrict__ dst) {
  int i = (blockIdx.x * 256 + threadIdx.x) * 4;      // total 1,179,648 elems
  if (i >= 1179648) return;
  const float* src;
  if (i < 1048576)      src = W0 + i;
  else if (i < 1114112) src = Wd + (i - 1048576);
  else                  src = Wup + (i - 1114112);
  float4 v = *(const float4*)src;
  union { u16 u[4]; uint2 q; } p;
  p.u[0] = f2b(v.x); p.u[1] = f2b(v.y); p.u[2] = f2b(v.z); p.u[3] = f2b(v.w);
  *(uint2*)(dst + i) = p.q;
}

// ---------------- Kernel 1: z = x @ W_down^T -> f32 (A reg-stage-converted) ----------------
__global__ __launch_bounds__(256) void zgemm_kernel(const float* __restrict__ x,
                                                    const u16* __restrict__ Wdb,
                                                    float* __restrict__ z) {
  __shared__ u16 As[64 * 32];
  __shared__ u16 Bs[64 * 32];
  const int tid = threadIdx.x;
  const int lane = tid & 63;
  const int w = tid >> 6;
  const int row0 = blockIdx.x * 64;
  f32x4 acc[4] = {{0,0,0,0},{0,0,0,0},{0,0,0,0},{0,0,0,0}};
  const int srow = tid >> 2, sk8 = tid & 3;
  int arow = row0 + srow; if (arow >= MTOT) arow = MTOT - 1;
  const float* agf = x + (size_t)arow * 1024 + sk8 * 8;
  const u16* bg = Wdb + (size_t)srow * 1024 + sk8 * 8;
  u16* al = As + tid * 8;
  u16* bl = Bs + tid * 8;
  const int klo = (lane >> 4) * 8;
  for (int k0 = 0; k0 < 1024; k0 += 32) {
    gload_lds16(bg + k0, bl);
    float4 q0 = *(const float4*)(agf + k0);
    float4 q1 = *(const float4*)(agf + k0 + 4);
    cvt_store8(al, q0, q1);
    __syncthreads();
    bf16x8 a = *(const bf16x8*)(As + (w * 16 + (lane & 15)) * 32 + klo);
#pragma unroll
    for (int fc = 0; fc < 4; ++fc) {
      bf16x8 bb = *(const bf16x8*)(Bs + (fc * 16 + (lane & 15)) * 32 + klo);
      acc[fc] = mfma16(a, bb, acc[fc]);
    }
    __syncthreads();
  }
  const int crow = (lane >> 4) * 4, ccol = lane & 15;
#pragma unroll
  for (int fc = 0; fc < 4; ++fc) {
#pragma unroll
    for (int i = 0; i < 4; ++i) {
      int gr = row0 + w * 16 + crow + i;
      if (gr < MTOT) z[(size_t)gr * 64 + fc * 16 + ccol] = acc[fc][i];
    }
  }
}

// ---------------- Kernel 2a: conv weight transpose f32[e][co][ci][3][3] -> bf16[e][tap][co][ci] ----------------
__global__ __launch_bounds__(256) void convwt_kernel(const float* __restrict__ cw, u16* __restrict__ cwt) {
  int idx = blockIdx.x * 256 + threadIdx.x;          // 3*9*64*64 = 110592 total
  if (idx >= 3 * 9 * 64 * 64) return;
  int ci = idx & 63;
  int co = (idx >> 6) & 63;
  int rest = idx >> 12;           // e*9 + tap
  int tap = rest % 9;
  int e = rest / 9;
  cwt[idx] = f2b(cw[((size_t)(e * 64 + co) * 64 + ci) * 9 + tap]);
}

// ---------------- Kernel 2b: gate stage 1 — per-chunk partial channel sums (448 blocks) ----------------
__global__ __launch_bounds__(256) void gate1_kernel(const float* __restrict__ z, float* __restrict__ pp) {
  int b = blockIdx.y, q = blockIdx.x;   // q in [0,56): rows 1+q*126 .. 1+q*126+125
  int tid = threadIdx.x;
  int c = tid & 63, part = tid >> 6;
  const float* zb = z + (size_t)b * N_ * 64;
  int n0 = 1 + q * 126;
  float s = 0.0f;
  for (int n = n0 + part; n < n0 + 126; n += 4) s += zb[(size_t)n * 64 + c];
  __shared__ float red[4][64];
  red[part][c] = s;
  __syncthreads();
  if (tid < 64)
    pp[((size_t)b * 56 + q) * 64 + tid] = red[0][tid] + red[1][tid] + red[2][tid] + red[3][tid];
}

// ---------------- Kernel 2c: gate stage 2 — pooled mean, scores, argmax, cls row ----------------
__global__ __launch_bounds__(64) void gate2_kernel(const float* __restrict__ pp, const float* __restrict__ z,
                                                   const float* __restrict__ Wg, const float* __restrict__ bg,
                                                   int* __restrict__ gidx, u16* __restrict__ lora) {
  int b = blockIdx.x;
  int c = threadIdx.x;                  // 0..63
  float s = 0.0f;
  for (int q = 0; q < 56; ++q) s += pp[((size_t)b * 56 + q) * 64 + c];
  __shared__ float pl[64];
  pl[c] = s * (1.0f / 7056.0f);
  const float* zb = z + (size_t)b * N_ * 64;
  lora[(size_t)b * N_ * 64 + c] = f2b(zb[c]);   // cls_embed, NOT scaled
  __syncthreads();
  if (c == 0) {
    float best = 0.0f; int bi = 0;
    for (int e = 0; e < 3; ++e) {
      float sc = bg[e];
      for (int r = 0; r < 64; ++r) sc += pl[r] * Wg[e * 64 + r];
      if (e == 0 || sc > best) { best = sc; bi = e; }   // first-max semantics
    }
    gidx[b] = bi;
  }
}

// ---------------- Kernel 3: fused separable bicubic upsample (z -> up, layout (y,x,c) bf16) ----------------
__global__ __launch_bounds__(256) void up_kernel(const float* __restrict__ z, const int* __restrict__ gidx,
                                                 u16* __restrict__ up) {
  int b = blockIdx.z;
  int r = rate_of(gidx[b]);
  int H = 84 * r;
  int y = blockIdx.y; if (y >= H) return;
  int c = threadIdx.x & 63, s = threadIdx.x >> 6;
  int x0 = blockIdx.x * 16 + s * 4;
  if (x0 >= H) return;
  float inv = 1.0f / (float)r;
  float sy = (y + 0.5f) * inv - 0.5f;
  float fy = floorf(sy);
  int iy0 = (int)fy;
  float wy[4]; int yi[4];
#pragma unroll
  for (int u = 0; u < 4; ++u) { wy[u] = cubicw(sy - (fy - 1.0f + u)); yi[u] = iclamp(iy0 - 1 + u, 0, 83); }
  const float* zb = z + ((size_t)b * N_ + 1) * 64;
  u16* ub = up + (size_t)b * UPB_STRIDE;
#pragma unroll
  for (int xx = 0; xx < 4; ++xx) {
    int X = x0 + xx; if (X >= H) break;
    float sx = (X + 0.5f) * inv - 0.5f;
    float fx = floorf(sx);
    int ix0 = (int)fx;
    float acc = 0.0f;
#pragma unroll
    for (int v = 0; v < 4; ++v) {
      float wv = cubicw(sx - (fx - 1.0f + v));
      int xiv = iclamp(ix0 - 1 + v, 0, 83);
#pragma unroll
      for (int u = 0; u < 4; ++u)
        acc += wy[u] * wv * zb[((size_t)yi[u] * 84 + xiv) * 64 + c];
    }
    ub[((size_t)y * H + X) * 64 + c] = f2b(acc);
  }
}

// ---------------- Kernel 4: implicit-GEMM 3x3 conv (zero-pad) + bias, dbuf weight prefetch ----------------
__global__ __launch_bounds__(256) void conv_kernel(const u16* __restrict__ up, const u16* __restrict__ cwt,
                                                   const float* __restrict__ cb, const int* __restrict__ gidx,
                                                   u16* __restrict__ cvo) {
  int b = blockIdx.z;
  int e = gidx[b];
  int r = rate_of(e);
  int H = 84 * r;
  int tx = blockIdx.x, ty = blockIdx.y;
  if (tx * 8 >= H || ty * 8 >= H) return;
  __shared__ u16 halo[100 * 64];   // 10x10 pixels x 64 c_in (12.8 KB)
  __shared__ u16 Bw[2][4096];      // double-buffered [co][ci] tap tile (16 KB)
  int tid = threadIdx.x, lane = tid & 63, w = tid >> 6;
  const u16* ub = up + (size_t)b * UPB_STRIDE;
  const u16* wte = cwt + (size_t)e * 9 * 4096;
  // prefetch tap-0 weights (async) while staging the halo
  gload_lds16(wte + tid * 8, Bw[0] + tid * 8);
  gload_lds16(wte + 2048 + tid * 8, Bw[0] + 2048 + tid * 8);
  for (int li = tid; li < 800; li += 256) {
    int pix = li >> 3, cq = li & 7;
    int hy = pix / 10, hx = pix - hy * 10;
    int iy = ty * 8 - 1 + hy, ix = tx * 8 - 1 + hx;
    uint4 v = {0u, 0u, 0u, 0u};
    if (iy >= 0 && iy < H && ix >= 0 && ix < H)
      v = *(const uint4*)(ub + ((size_t)iy * H + ix) * 64 + cq * 8);
    *(uint4*)(halo + pix * 64 + cq * 8) = v;
  }
  __syncthreads();                 // halo + Bw[0] ready
  f32x4 acc[4] = {{0,0,0,0},{0,0,0,0},{0,0,0,0},{0,0,0,0}};
  int p = w * 16 + (lane & 15);
  int py = p >> 3, px = p & 7;
  int klo = (lane >> 4) * 8;
  for (int tap = 0; tap < 9; ++tap) {
    if (tap < 8) {                 // prefetch next tap into the other buffer
      const u16* wt = wte + (size_t)(tap + 1) * 4096;
      gload_lds16(wt + tid * 8, Bw[(tap + 1) & 1] + tid * 8);
      gload_lds16(wt + 2048 + tid * 8, Bw[(tap + 1) & 1] + 2048 + tid * 8);
    }
    int dy = tap / 3, dx = tap - dy * 3;
    const u16* hb = halo + ((py + dy) * 10 + (px + dx)) * 64 + klo;
    const u16* bwc = Bw[tap & 1];
#pragma unroll
    for (int kk = 0; kk < 2; ++kk) {
      bf16x8 a = *(const bf16x8*)(hb + kk * 32);
#pragma unroll
      for (int fc = 0; fc < 4; ++fc) {
        bf16x8 bb = *(const bf16x8*)(bwc + (fc * 16 + (lane & 15)) * 64 + kk * 32 + klo);
        acc[fc] = mfma16(a, bb, acc[fc]);
      }
    }
    __syncthreads();               // reads of Bw[tap&1] done; prefetched Bw[(tap+1)&1] drained
  }
  int crow = (lane >> 4) * 4, ccol = lane & 15;
  u16* cvb = cvo + (size_t)b * UPB_STRIDE;
#pragma unroll
  for (int fc = 0; fc < 4; ++fc) {
    int co = fc * 16 + ccol;
    float bias = cb[e * 64 + co];
#pragma unroll
    for (int i = 0; i < 4; ++i) {
      int pd = w * 16 + crow + i;
      int gy = ty * 8 + (pd >> 3), gx = tx * 8 + (pd & 7);
      if (gy < H && gx < H)
        cvb[((size_t)gy * H + gx) * 64 + co] = f2b(acc[fc][i] + bias);
    }
  }
}

// ---------------- Kernel 5: bicubic downsample * SCALING -> lora rows 1..7056 ----------------
__global__ __launch_bounds__(256) void down_kernel(const u16* __restrict__ cvo, const int* __restrict__ gidx,
                                                   u16* __restrict__ lora) {
  int b = blockIdx.z;
  int r = rate_of(gidx[b]);
  int H = 84 * r;
  int tid = threadIdx.x;
  int c = tid & 63, s = tid >> 6;
  int y = blockIdx.y;
  int x = blockIdx.x * 4 + s;
  float fr = (float)r;
  float sy = (y + 0.5f) * fr - 0.5f;
  float fy = floorf(sy);
  int iy0 = (int)fy;
  float wy[4]; int yi[4];
#pragma unroll
  for (int u = 0; u < 4; ++u) { wy[u] = cubicw(sy - (fy - 1.0f + u)); yi[u] = iclamp(iy0 - 1 + u, 0, H - 1); }
  float sx = (x + 0.5f) * fr - 0.5f;
  float fx = floorf(sx);
  int ix0 = (int)fx;
  float wx[4]; int xi[4];
#pragma unroll
  for (int v = 0; v < 4; ++v) { wx[v] = cubicw(sx - (fx - 1.0f + v)); xi[v] = iclamp(ix0 - 1 + v, 0, H - 1); }
  const u16* cbase = cvo + (size_t)b * UPB_STRIDE;
  float acc = 0.0f;
#pragma unroll
  for (int u = 0; u < 4; ++u)
#pragma unroll
    for (int v = 0; v < 4; ++v)
      acc += wy[u] * wx[v] * b2f(cbase[((size_t)yi[u] * H + xi[v]) * 64 + c]);
  lora[((size_t)b * N_ + 1 + y * 84 + x) * 64 + c] = f2b(acc * SCALING_F);
}

// ---------------- Kernel 6: main GEMM out = x@W0^T + b0 + lora@W_up^T (fused K=1024+64) ----------------
#define MAIN_COMPUTE()                                                                       \
  {                                                                                          \
    bf16x8 af[4], bfr[4];                                                                    \
    _Pragma("unroll")                                                                        \
    for (int fm = 0; fm < 4; ++fm)                                                           \
      af[fm] = *(const bf16x8*)(As + (wr * 64 + fm * 16 + (lane & 15)) * 32 + klo);          \
    _Pragma("unroll")                                                                        \
    for (int fc = 0; fc < 4; ++fc)                                                           \
      bfr[fc] = *(const bf16x8*)(Bs + (wc * 64 + fc * 16 + (lane & 15)) * 32 + klo);         \
    _Pragma("unroll")                                                                        \
    for (int fm = 0; fm < 4; ++fm) {                                                         \
      _Pragma("unroll")                                                                      \
      for (int fc = 0; fc < 4; ++fc)                                                         \
        acc[fm][fc] = mfma16(af[fm], bfr[fc], acc[fm][fc]);                                  \
    }                                                                                        \
  }

__global__ __launch_bounds__(256) void main_gemm(const float* __restrict__ x, const u16* __restrict__ W0b,
                                                 const float* __restrict__ b0, const u16* __restrict__ lora,
                                                 const u16* __restrict__ Wub, float* __restrict__ out) {
  __shared__ u16 As[128 * 32];
  __shared__ u16 Bs[128 * 32];
  int tid = threadIdx.x, lane = tid & 63, w = tid >> 6;
  // XCD-chunked swizzle (3536 = 8*442 blocks), col-fastest within a row-panel
  int bid = blockIdx.x;
  int wg = (bid & 7) * 442 + (bid >> 3);
  int row0 = (wg >> 3) * 128, col0 = (wg & 7) * 128;
  int wr = w >> 1, wc = w & 1;
  f32x4 acc[4][4] = {};
  int srow = tid >> 2, sk8 = tid & 3;
  int ar0 = row0 + srow; if (ar0 >= MTOT) ar0 = MTOT - 1;
  int ar1 = row0 + srow + 64; if (ar1 >= MTOT) ar1 = MTOT - 1;
  const float* agf0 = x + (size_t)ar0 * 1024 + sk8 * 8;
  const float* agf1 = x + (size_t)ar1 * 1024 + sk8 * 8;
  const u16* bg0 = W0b + (size_t)(col0 + srow) * 1024 + sk8 * 8;
  const u16* bg1 = W0b + (size_t)(col0 + srow + 64) * 1024 + sk8 * 8;
  u16* al0 = As + tid * 8; u16* al1 = As + tid * 8 + 2048;
  u16* bl0 = Bs + tid * 8; u16* bl1 = Bs + tid * 8 + 2048;
  const int klo = (lane >> 4) * 8;
  for (int k0 = 0; k0 < 1024; k0 += 32) {
    gload_lds16(bg0 + k0, bl0);
    gload_lds16(bg1 + k0, bl1);
    float4 q0 = *(const float4*)(agf0 + k0);
    float4 q1 = *(const float4*)(agf0 + k0 + 4);
    float4 q2 = *(const float4*)(agf1 + k0);
    float4 q3 = *(const float4*)(agf1 + k0 + 4);
    cvt_store8(al0, q0, q1);
    cvt_store8(al1, q2, q3);
    __syncthreads();
    MAIN_COMPUTE();
    __syncthreads();
  }
  // fused lora K-extension (K2 = 64), bf16 sources -> gload_lds
  const u16* lg0 = lora + (size_t)ar0 * 64 + sk8 * 8;
  const u16* lg1 = lora + (size_t)ar1 * 64 + sk8 * 8;
  const u16* ug0 = Wub + (size_t)(col0 + srow) * 64 + sk8 * 8;
  const u16* ug1 = Wub + (size_t)(col0 + srow + 64) * 64 + sk8 * 8;
  for (int k0 = 0; k0 < 64; k0 += 32) {
    gload_lds16(lg0 + k0, al0);
    gload_lds16(lg1 + k0, al1);
    gload_lds16(ug0 + k0, bl0);
    gload_lds16(ug1 + k0, bl1);
    __syncthreads();
    MAIN_COMPUTE();
    __syncthreads();
  }
  int crow = (lane >> 4) * 4, ccol = lane & 15;
#pragma unroll
  for (int fm = 0; fm < 4; ++fm) {
    int grb = row0 + wr * 64 + fm * 16 + crow;
#pragma unroll
    for (int fc = 0; fc < 4; ++fc) {
      int gc = col0 + wc * 64 + fc * 16 + ccol;
      float bias = b0[gc];
#pragma unroll
      for (int i = 0; i < 4; ++i) {
        int gr = grb + i;
        if (gr < MTOT) out[(size_t)gr * 1024 + gc] = acc[fm][fc][i] + bias;
      }
    }
  }
}

extern "C" void kernel_launch(void* const* d_in, const int* in_sizes, int n_in,
                              void* d_out, int out_size, void* d_ws, size_t ws_size,
                              hipStream_t stream) {
  const float* x   = (const float*)d_in[0];
  const float* W0  = (const float*)d_in[1];
  const float* b0  = (const float*)d_in[2];
  const float* Wd  = (const float*)d_in[3];
  const float* Wg  = (const float*)d_in[4];
  const float* bg  = (const float*)d_in[5];
  const float* cw  = (const float*)d_in[6];
  const float* cb  = (const float*)d_in[7];
  const float* Wup = (const float*)d_in[8];
  char* ws = (char*)d_ws;
  float* z    = (float*)(ws + Z_OFF);
  u16* lora   = (u16*)(ws + LORA_OFF);
  int* gidx   = (int*)(ws + GIDX_OFF);
  u16* cwt    = (u16*)(ws + CWT_OFF);
  u16* W0b    = (u16*)(ws + W0B_OFF);
  u16* Wub    = (u16*)(ws + WUB_OFF);
  u16* up     = (u16*)(ws + UP_OFF);
  float* pp   = (float*)(ws + UP_OFF);   // pp[8][56][64] borrows UP region (dead until up_kernel)
  u16* cvo    = (u16*)(ws + CO_OFF);
  float* out  = (float*)d_out;
  u16* Wdb    = (u16*)(ws + WDB_OFF);

  cvtall_kernel<<<dim3(1152), dim3(256), 0, stream>>>(W0, Wd, Wup, W0b);
  convwt_kernel<<<dim3(432), dim3(256), 0, stream>>>(cw, cwt);
  zgemm_kernel<<<dim3(883), dim3(256), 0, stream>>>(x, Wdb, z);
  gate1_kernel<<<dim3(56, 8), dim3(256), 0, stream>>>(z, pp);
  gate2_kernel<<<dim3(8), dim3(64), 0, stream>>>(pp, z, Wg, bg, gidx, lora);
  up_kernel<<<dim3(21, 336, 8), dim3(256), 0, stream>>>(z, gidx, up);
  conv_kernel<<<dim3(42, 42, 8), dim3(256), 0, stream>>>(up, cwt, cb, gidx, cvo);
  down_kernel<<<dim3(21, 84, 8), dim3(256), 0, stream>>>(cvo, gidx, lora);
  main_gemm<<<dim3(3536), dim3(256), 0, stream>>>(x, W0b, b0, lora, Wub, out);
}

// Round 5
// 595.689 us; speedup vs baseline: 1.7598x; 1.0793x over previous
//
#include <hip/hip_runtime.h>
#include <stdint.h>

typedef unsigned short u16;
typedef __bf16 bf16x8 __attribute__((ext_vector_type(8)));
typedef float f32x4 __attribute__((ext_vector_type(4)));

#define B_ 8
#define N_ 7057
#define MTOT 56456
#define SCALING_F (1.0f/64.0f)

// ws layout (bytes, 16-aligned).
#define Z_OFF    0ull               // f32 z: 14,452,736
#define LORA_OFF 14452736ull        // bf16 lora: 7,226,368
#define GIDX_OFF 21679104ull        // int gate_idx[8] (+pad)
#define CWT_OFF  21679360ull        // bf16 conv_wt: 221,184
#define W0B_OFF  21900544ull        // bf16 W0: 2,097,152
#define WDB_OFF  23997696ull        // bf16 W_down: 131,072
#define WUB_OFF  24128768ull        // bf16 W_up: 131,072
#define UP_OFF   24259840ull        // bf16 up: 115,605,504 (pp[8][56][64] f32 borrows pre-up)
#define CO_OFF   139865344ull       // bf16 convout: 115,605,504 (ends 255,470,848)
#define XB_OFF   255470848ull       // bf16 xb [MTOT][1024]: 115,621,888 (fast path only)
#define WS_FAST  371092736ull       // bytes needed for fast path
#define WS_SLOW  255487232ull       // slow path: xb overlays CO (needs +16KB past CO)
#define UPB_STRIDE ((size_t)112896 * 64)  // per-batch elems (max rate 4)

__device__ __forceinline__ u16 f2b(float f) {
  __bf16 h = (__bf16)f;           // RNE
  union { __bf16 h; u16 u; } v; v.h = h; return v.u;
}
__device__ __forceinline__ float b2f(u16 u) {
  union { uint32_t i; float f; } v; v.i = ((uint32_t)u) << 16; return v.f;
}
__device__ __forceinline__ void gload_lds16(const void* g, void* l) {
  __builtin_amdgcn_global_load_lds(
      (const __attribute__((address_space(1))) uint32_t*)g,
      (__attribute__((address_space(3))) uint32_t*)l, 16, 0, 0);
}
__device__ __forceinline__ f32x4 mfma16(bf16x8 a, bf16x8 b, f32x4 c) {
  return __builtin_amdgcn_mfma_f32_16x16x32_bf16(a, b, c, 0, 0, 0);
}
__device__ __forceinline__ bf16x8 cvt8(float4 a, float4 b) {
  bf16x8 v;
  v[0] = (__bf16)a.x; v[1] = (__bf16)a.y; v[2] = (__bf16)a.z; v[3] = (__bf16)a.w;
  v[4] = (__bf16)b.x; v[5] = (__bf16)b.y; v[6] = (__bf16)b.z; v[7] = (__bf16)b.w;
  return v;
}
__device__ __forceinline__ float cubicw(float t) {
  const float a = -0.75f;
  float at = fabsf(t);
  float w1 = ((a + 2.0f) * at - (a + 3.0f)) * at * at + 1.0f;
  float w2 = (((at - 5.0f) * at + 8.0f) * at - 4.0f) * a;
  return at <= 1.0f ? w1 : (at < 2.0f ? w2 : 0.0f);
}
__device__ __forceinline__ int iclamp(int v, int lo, int hi) { return v < lo ? lo : (v > hi ? hi : v); }
__device__ __forceinline__ int rate_of(int e) { return e == 0 ? 2 : (e == 1 ? 1 : 4); }

// ---------------- Kernel 0: merged f32 -> bf16 weight convert (W0|Wd|Wup contiguous) ----------------
__global__ __launch_bounds__(256) void cvtall_kernel(const float* __restrict__ W0, const float* __restrict__ Wd,
                                                     const float* __restrict__ Wup, u16* __restrict__ dst) {
  int i = (blockIdx.x * 256 + threadIdx.x) * 4;      // total 1,179,648 elems
  if (i >= 1179648) return;
  const float* src;
  if (i < 1048576)      src = W0 + i;
  else if (i < 1114112) src = Wd + (i - 1048576);
  else                  src = Wup + (i - 1114112);
  float4 v = *(const float4*)src;
  union { u16 u[4]; uint2 q; } p;
  p.u[0] = f2b(v.x); p.u[1] = f2b(v.y); p.u[2] = f2b(v.z); p.u[3] = f2b(v.w);
  *(uint2*)(dst + i) = p.q;
}

// ---------------- Kernel 0b (fallback): x f32 -> bf16 grid-stride ----------------
__global__ __launch_bounds__(256) void cvtx_kernel(const float* __restrict__ x, u16* __restrict__ xb) {
  size_t stride = (size_t)gridDim.x * 256 * 8;
  for (size_t i = ((size_t)blockIdx.x * 256 + threadIdx.x) * 8; i < (size_t)MTOT * 1024; i += stride) {
    float4 a = *(const float4*)(x + i);
    float4 b = *(const float4*)(x + i + 4);
    *(bf16x8*)(xb + i) = cvt8(a, b);
  }
}

// ---------------- Kernel 1: z = x @ W_down^T -> f32; side-writes xb (bf16 x) ----------------
__global__ __launch_bounds__(256) void zgemm_kernel(const float* __restrict__ x,
                                                    const u16* __restrict__ Wdb,
                                                    float* __restrict__ z,
                                                    u16* __restrict__ xb) {
  __shared__ u16 As[64 * 32];
  __shared__ u16 Bs[64 * 32];
  const int tid = threadIdx.x;
  const int lane = tid & 63;
  const int w = tid >> 6;
  const int row0 = blockIdx.x * 64;
  f32x4 acc[4] = {{0,0,0,0},{0,0,0,0},{0,0,0,0},{0,0,0,0}};
  const int srow = tid >> 2, sk8 = tid & 3;
  int arow = row0 + srow; if (arow >= MTOT) arow = MTOT - 1;
  const float* agf = x + (size_t)arow * 1024 + sk8 * 8;
  const u16* bg = Wdb + (size_t)srow * 1024 + sk8 * 8;
  u16* xbp = xb ? (xb + (size_t)arow * 1024 + sk8 * 8) : nullptr;
  u16* al = As + tid * 8;
  u16* bl = Bs + tid * 8;
  const int klo = (lane >> 4) * 8;
  for (int k0 = 0; k0 < 1024; k0 += 32) {
    gload_lds16(bg + k0, bl);
    float4 q0 = *(const float4*)(agf + k0);
    float4 q1 = *(const float4*)(agf + k0 + 4);
    bf16x8 cv = cvt8(q0, q1);
    *(bf16x8*)al = cv;
    if (xbp) *(bf16x8*)(xbp + k0) = cv;   // bf16 x side-product (fast path)
    __syncthreads();
    bf16x8 a = *(const bf16x8*)(As + (w * 16 + (lane & 15)) * 32 + klo);
#pragma unroll
    for (int fc = 0; fc < 4; ++fc) {
      bf16x8 bb = *(const bf16x8*)(Bs + (fc * 16 + (lane & 15)) * 32 + klo);
      acc[fc] = mfma16(a, bb, acc[fc]);
    }
    __syncthreads();
  }
  const int crow = (lane >> 4) * 4, ccol = lane & 15;
#pragma unroll
  for (int fc = 0; fc < 4; ++fc) {
#pragma unroll
    for (int i = 0; i < 4; ++i) {
      int gr = row0 + w * 16 + crow + i;
      if (gr < MTOT) z[(size_t)gr * 64 + fc * 16 + ccol] = acc[fc][i];
    }
  }
}

// ---------------- Kernel 2a: conv weight transpose f32[e][co][ci][3][3] -> bf16[e][tap][co][ci] ----------------
__global__ __launch_bounds__(256) void convwt_kernel(const float* __restrict__ cw, u16* __restrict__ cwt) {
  int idx = blockIdx.x * 256 + threadIdx.x;          // 3*9*64*64 = 110592 total
  if (idx >= 3 * 9 * 64 * 64) return;
  int ci = idx & 63;
  int co = (idx >> 6) & 63;
  int rest = idx >> 12;           // e*9 + tap
  int tap = rest % 9;
  int e = rest / 9;
  cwt[idx] = f2b(cw[((size_t)(e * 64 + co) * 64 + ci) * 9 + tap]);
}

// ---------------- Kernel 2b: gate stage 1 — per-chunk partial channel sums ----------------
__global__ __launch_bounds__(256) void gate1_kernel(const float* __restrict__ z, float* __restrict__ pp) {
  int b = blockIdx.y, q = blockIdx.x;   // q in [0,56)
  int tid = threadIdx.x;
  int c = tid & 63, part = tid >> 6;
  const float* zb = z + (size_t)b * N_ * 64;
  int n0 = 1 + q * 126;
  float s = 0.0f;
  for (int n = n0 + part; n < n0 + 126; n += 4) s += zb[(size_t)n * 64 + c];
  __shared__ float red[4][64];
  red[part][c] = s;
  __syncthreads();
  if (tid < 64)
    pp[((size_t)b * 56 + q) * 64 + tid] = red[0][tid] + red[1][tid] + red[2][tid] + red[3][tid];
}

// ---------------- Kernel 2c: gate stage 2 — pooled mean, scores, argmax, cls row ----------------
__global__ __launch_bounds__(64) void gate2_kernel(const float* __restrict__ pp, const float* __restrict__ z,
                                                   const float* __restrict__ Wg, const float* __restrict__ bg,
                                                   int* __restrict__ gidx, u16* __restrict__ lora) {
  int b = blockIdx.x;
  int c = threadIdx.x;                  // 0..63
  float s = 0.0f;
  for (int q = 0; q < 56; ++q) s += pp[((size_t)b * 56 + q) * 64 + c];
  __shared__ float pl[64];
  pl[c] = s * (1.0f / 7056.0f);
  const float* zb = z + (size_t)b * N_ * 64;
  lora[(size_t)b * N_ * 64 + c] = f2b(zb[c]);   // cls_embed, NOT scaled
  __syncthreads();
  if (c == 0) {
    float best = 0.0f; int bi = 0;
    for (int e = 0; e < 3; ++e) {
      float sc = bg[e];
      for (int r = 0; r < 64; ++r) sc += pl[r] * Wg[e * 64 + r];
      if (e == 0 || sc > best) { best = sc; bi = e; }   // first-max semantics
    }
    gidx[b] = bi;
  }
}

// ---------------- Kernel 3: fused separable bicubic upsample (z -> up, (y,x,c) bf16) ----------------
__global__ __launch_bounds__(256) void up_kernel(const float* __restrict__ z, const int* __restrict__ gidx,
                                                 u16* __restrict__ up) {
  int b = blockIdx.z;
  int r = rate_of(gidx[b]);
  int H = 84 * r;
  int y = blockIdx.y; if (y >= H) return;
  int c = threadIdx.x & 63, s = threadIdx.x >> 6;
  int x0 = blockIdx.x * 16 + s * 4;
  if (x0 >= H) return;
  float inv = 1.0f / (float)r;
  float sy = (y + 0.5f) * inv - 0.5f;
  float fy = floorf(sy);
  int iy0 = (int)fy;
  float wy[4]; int yi[4];
#pragma unroll
  for (int u = 0; u < 4; ++u) { wy[u] = cubicw(sy - (fy - 1.0f + u)); yi[u] = iclamp(iy0 - 1 + u, 0, 83); }
  const float* zb = z + ((size_t)b * N_ + 1) * 64;
  u16* ub = up + (size_t)b * UPB_STRIDE;
#pragma unroll
  for (int xx = 0; xx < 4; ++xx) {
    int X = x0 + xx; if (X >= H) break;
    float sx = (X + 0.5f) * inv - 0.5f;
    float fx = floorf(sx);
    int ix0 = (int)fx;
    float acc = 0.0f;
#pragma unroll
    for (int v = 0; v < 4; ++v) {
      float wv = cubicw(sx - (fx - 1.0f + v));
      int xiv = iclamp(ix0 - 1 + v, 0, 83);
#pragma unroll
      for (int u = 0; u < 4; ++u)
        acc += wy[u] * wv * zb[((size_t)yi[u] * 84 + xiv) * 64 + c];
    }
    ub[((size_t)y * H + X) * 64 + c] = f2b(acc);
  }
}

// ---------------- Kernel 4: implicit-GEMM 3x3 conv (zero-pad) + bias, dbuf weight prefetch ----------------
__global__ __launch_bounds__(256) void conv_kernel(const u16* __restrict__ up, const u16* __restrict__ cwt,
                                                   const float* __restrict__ cb, const int* __restrict__ gidx,
                                                   u16* __restrict__ cvo) {
  int b = blockIdx.z;
  int e = gidx[b];
  int r = rate_of(e);
  int H = 84 * r;
  int tx = blockIdx.x, ty = blockIdx.y;
  if (tx * 8 >= H || ty * 8 >= H) return;
  __shared__ u16 halo[100 * 64];
  __shared__ u16 Bw[2][4096];
  int tid = threadIdx.x, lane = tid & 63, w = tid >> 6;
  const u16* ub = up + (size_t)b * UPB_STRIDE;
  const u16* wte = cwt + (size_t)e * 9 * 4096;
  gload_lds16(wte + tid * 8, Bw[0] + tid * 8);
  gload_lds16(wte + 2048 + tid * 8, Bw[0] + 2048 + tid * 8);
  for (int li = tid; li < 800; li += 256) {
    int pix = li >> 3, cq = li & 7;
    int hy = pix / 10, hx = pix - hy * 10;
    int iy = ty * 8 - 1 + hy, ix = tx * 8 - 1 + hx;
    uint4 v = {0u, 0u, 0u, 0u};
    if (iy >= 0 && iy < H && ix >= 0 && ix < H)
      v = *(const uint4*)(ub + ((size_t)iy * H + ix) * 64 + cq * 8);
    *(uint4*)(halo + pix * 64 + cq * 8) = v;
  }
  __syncthreads();
  f32x4 acc[4] = {{0,0,0,0},{0,0,0,0},{0,0,0,0},{0,0,0,0}};
  int p = w * 16 + (lane & 15);
  int py = p >> 3, px = p & 7;
  int klo = (lane >> 4) * 8;
  for (int tap = 0; tap < 9; ++tap) {
    if (tap < 8) {
      const u16* wt = wte + (size_t)(tap + 1) * 4096;
      gload_lds16(wt + tid * 8, Bw[(tap + 1) & 1] + tid * 8);
      gload_lds16(wt + 2048 + tid * 8, Bw[(tap + 1) & 1] + 2048 + tid * 8);
    }
    int dy = tap / 3, dx = tap - dy * 3;
    const u16* hb = halo + ((py + dy) * 10 + (px + dx)) * 64 + klo;
    const u16* bwc = Bw[tap & 1];
#pragma unroll
    for (int kk = 0; kk < 2; ++kk) {
      bf16x8 a = *(const bf16x8*)(hb + kk * 32);
#pragma unroll
      for (int fc = 0; fc < 4; ++fc) {
        bf16x8 bb = *(const bf16x8*)(bwc + (fc * 16 + (lane & 15)) * 64 + kk * 32 + klo);
        acc[fc] = mfma16(a, bb, acc[fc]);
      }
    }
    __syncthreads();
  }
  int crow = (lane >> 4) * 4, ccol = lane & 15;
  u16* cvb = cvo + (size_t)b * UPB_STRIDE;
#pragma unroll
  for (int fc = 0; fc < 4; ++fc) {
    int co = fc * 16 + ccol;
    float bias = cb[e * 64 + co];
#pragma unroll
    for (int i = 0; i < 4; ++i) {
      int pd = w * 16 + crow + i;
      int gy = ty * 8 + (pd >> 3), gx = tx * 8 + (pd & 7);
      if (gy < H && gx < H)
        cvb[((size_t)gy * H + gx) * 64 + co] = f2b(acc[fc][i] + bias);
    }
  }
}

// ---------------- Kernel 5: bicubic downsample * SCALING -> lora rows 1..7056 ----------------
__global__ __launch_bounds__(256) void down_kernel(const u16* __restrict__ cvo, const int* __restrict__ gidx,
                                                   u16* __restrict__ lora) {
  int b = blockIdx.z;
  int r = rate_of(gidx[b]);
  int H = 84 * r;
  int tid = threadIdx.x;
  int c = tid & 63, s = tid >> 6;
  int y = blockIdx.y;
  int x = blockIdx.x * 4 + s;
  float fr = (float)r;
  float sy = (y + 0.5f) * fr - 0.5f;
  float fy = floorf(sy);
  int iy0 = (int)fy;
  float wy[4]; int yi[4];
#pragma unroll
  for (int u = 0; u < 4; ++u) { wy[u] = cubicw(sy - (fy - 1.0f + u)); yi[u] = iclamp(iy0 - 1 + u, 0, H - 1); }
  float sx = (x + 0.5f) * fr - 0.5f;
  float fx = floorf(sx);
  int ix0 = (int)fx;
  float wx[4]; int xi[4];
#pragma unroll
  for (int v = 0; v < 4; ++v) { wx[v] = cubicw(sx - (fx - 1.0f + v)); xi[v] = iclamp(ix0 - 1 + v, 0, H - 1); }
  const u16* cbase = cvo + (size_t)b * UPB_STRIDE;
  float acc = 0.0f;
#pragma unroll
  for (int u = 0; u < 4; ++u)
#pragma unroll
    for (int v = 0; v < 4; ++v)
      acc += wy[u] * wx[v] * b2f(cbase[((size_t)yi[u] * H + xi[v]) * 64 + c]);
  lora[((size_t)b * N_ + 1 + y * 84 + x) * 64 + c] = f2b(acc * SCALING_F);
}

// ---------------- Kernel 6: main GEMM out = xb@W0b^T + b0 + lora@Wub^T ----------------
// BK=64, XOR-swizzled LDS (chunk ^= row&7) via pre-swizzled global source (rule #21).
__global__ __launch_bounds__(256) void main_gemm(const u16* __restrict__ xb, const u16* __restrict__ W0b,
                                                 const float* __restrict__ b0, const u16* __restrict__ lora,
                                                 const u16* __restrict__ Wub, float* __restrict__ out) {
  __shared__ u16 As[128 * 64];   // 16 KB
  __shared__ u16 Bs[128 * 64];   // 16 KB
  int tid = threadIdx.x, lane = tid & 63, w = tid >> 6;
  int bid = blockIdx.x;
  int wg = (bid & 7) * 442 + (bid >> 3);      // XCD-chunked swizzle (3536 = 8*442, bijective)
  int row0 = (wg >> 3) * 128, col0 = (wg & 7) * 128;
  int wr = w >> 1, wc = w & 1;
  f32x4 acc[4][4] = {};
  // staging: 4 passes x 256 thr x 16B; pass p covers rows p*32..p*32+31
  int srow = tid >> 3;          // 0..31
  int schunk = tid & 7;         // 0..7 (16B k-chunks within a 64-elem row)
  int sch8 = ((schunk ^ (srow & 7)) << 3);    // pre-swizzled global k-offset (elems)
  int ar[4]; int br[4];
  u16* aldst[4]; u16* bldst[4];
#pragma unroll
  for (int p = 0; p < 4; ++p) {
    int rr = row0 + p * 32 + srow;
    ar[p] = rr >= MTOT ? MTOT - 1 : rr;
    br[p] = col0 + p * 32 + srow;
    aldst[p] = As + (p * 32 + srow) * 64 + schunk * 8;
    bldst[p] = Bs + (p * 32 + srow) * 64 + schunk * 8;
  }
  for (int k0 = 0; k0 < 1024; k0 += 64) {
#pragma unroll
    for (int p = 0; p < 4; ++p)
      gload_lds16(xb + (size_t)ar[p] * 1024 + k0 + sch8, aldst[p]);
#pragma unroll
    for (int p = 0; p < 4; ++p)
      gload_lds16(W0b + (size_t)br[p] * 1024 + k0 + sch8, bldst[p]);
    __syncthreads();
#pragma unroll
    for (int kk = 0; kk < 2; ++kk) {
      int pc = (((kk << 2) + (lane >> 4)) ^ (lane & 7)) << 3;   // swizzled read chunk
      bf16x8 af[4], bfr[4];
#pragma unroll
      for (int fm = 0; fm < 4; ++fm)
        af[fm] = *(const bf16x8*)(As + (wr * 64 + fm * 16 + (lane & 15)) * 64 + pc);
#pragma unroll
      for (int fc = 0; fc < 4; ++fc)
        bfr[fc] = *(const bf16x8*)(Bs + (wc * 64 + fc * 16 + (lane & 15)) * 64 + pc);
#pragma unroll
      for (int fm = 0; fm < 4; ++fm)
#pragma unroll
        for (int fc = 0; fc < 4; ++fc)
          acc[fm][fc] = mfma16(af[fm], bfr[fc], acc[fm][fc]);
    }
    __syncthreads();
  }
  // lora K-extension: one BK=64 step (rows stride 64 elems = exactly one LDS row)
#pragma unroll
  for (int p = 0; p < 4; ++p)
    gload_lds16(lora + (size_t)ar[p] * 64 + sch8, aldst[p]);
#pragma unroll
  for (int p = 0; p < 4; ++p)
    gload_lds16(Wub + (size_t)br[p] * 64 + sch8, bldst[p]);
  __syncthreads();
#pragma unroll
  for (int kk = 0; kk < 2; ++kk) {
    int pc = (((kk << 2) + (lane >> 4)) ^ (lane & 7)) << 3;
    bf16x8 af[4], bfr[4];
#pragma unroll
    for (int fm = 0; fm < 4; ++fm)
      af[fm] = *(const bf16x8*)(As + (wr * 64 + fm * 16 + (lane & 15)) * 64 + pc);
#pragma unroll
    for (int fc = 0; fc < 4; ++fc)
      bfr[fc] = *(const bf16x8*)(Bs + (wc * 64 + fc * 16 + (lane & 15)) * 64 + pc);
#pragma unroll
    for (int fm = 0; fm < 4; ++fm)
#pragma unroll
      for (int fc = 0; fc < 4; ++fc)
        acc[fm][fc] = mfma16(af[fm], bfr[fc], acc[fm][fc]);
  }
  __syncthreads();
  int crow = (lane >> 4) * 4, ccol = lane & 15;
#pragma unroll
  for (int fm = 0; fm < 4; ++fm) {
    int grb = row0 + wr * 64 + fm * 16 + crow;
#pragma unroll
    for (int fc = 0; fc < 4; ++fc) {
      int gc = col0 + wc * 64 + fc * 16 + ccol;
      float bias = b0[gc];
#pragma unroll
      for (int i = 0; i < 4; ++i) {
        int gr = grb + i;
        if (gr < MTOT) out[(size_t)gr * 1024 + gc] = acc[fm][fc][i] + bias;
      }
    }
  }
}

extern "C" void kernel_launch(void* const* d_in, const int* in_sizes, int n_in,
                              void* d_out, int out_size, void* d_ws, size_t ws_size,
                              hipStream_t stream) {
  const float* x   = (const float*)d_in[0];
  const float* W0  = (const float*)d_in[1];
  const float* b0  = (const float*)d_in[2];
  const float* Wd  = (const float*)d_in[3];
  const float* Wg  = (const float*)d_in[4];
  const float* bg  = (const float*)d_in[5];
  const float* cw  = (const float*)d_in[6];
  const float* cb  = (const float*)d_in[7];
  const float* Wup = (const float*)d_in[8];
  char* ws = (char*)d_ws;
  float* z    = (float*)(ws + Z_OFF);
  u16* lora   = (u16*)(ws + LORA_OFF);
  int* gidx   = (int*)(ws + GIDX_OFF);
  u16* cwt    = (u16*)(ws + CWT_OFF);
  u16* W0b    = (u16*)(ws + W0B_OFF);
  u16* Wdb    = (u16*)(ws + WDB_OFF);
  u16* Wub    = (u16*)(ws + WUB_OFF);
  u16* up     = (u16*)(ws + UP_OFF);
  float* pp   = (float*)(ws + UP_OFF);   // pp[8][56][64] borrows UP region (dead until up_kernel)
  u16* cvo    = (u16*)(ws + CO_OFF);
  float* out  = (float*)d_out;

  const bool fast = ws_size >= WS_FAST;          // constant across calls -> deterministic
  u16* xb = fast ? (u16*)(ws + XB_OFF) : (u16*)(ws + CO_OFF);

  cvtall_kernel<<<dim3(1152), dim3(256), 0, stream>>>(W0, Wd, Wup, W0b);
  convwt_kernel<<<dim3(432), dim3(256), 0, stream>>>(cw, cwt);
  zgemm_kernel<<<dim3(883), dim3(256), 0, stream>>>(x, Wdb, z, fast ? xb : nullptr);
  gate1_kernel<<<dim3(56, 8), dim3(256), 0, stream>>>(z, pp);
  gate2_kernel<<<dim3(8), dim3(64), 0, stream>>>(pp, z, Wg, bg, gidx, lora);
  up_kernel<<<dim3(21, 336, 8), dim3(256), 0, stream>>>(z, gidx, up);
  conv_kernel<<<dim3(42, 42, 8), dim3(256), 0, stream>>>(up, cwt, cb, gidx, cvo);
  down_kernel<<<dim3(21, 84, 8), dim3(256), 0, stream>>>(cvo, gidx, lora);
  if (!fast)
    cvtx_kernel<<<dim3(2048), dim3(256), 0, stream>>>(x, xb);  // xb overlays CO (cvo now dead)
  main_gemm<<<dim3(3536), dim3(256), 0, stream>>>(xb, W0b, b0, lora, Wub, out);
}